// Round 10
// baseline (112.129 us; speedup 1.0000x reference)
//
#include <hip/hip_runtime.h>

#define NMAX   64
#define NSITES 12
#define SPLIT  4      // threads per element-pair slot (3 sites each)
#define ELEMS  2      // elements per thread (row reads amortized)
#define BLOCK  256
#define RS     68     // LDS row stride (floats): rows 16B-aligned

#define B_SOFT 0.01f
#define PAD_C  4.0e4f          // sentinel coord -> r2 ~3e9 -> clamped to top bin
#define R2_LO  0.0009765625f   // 2^-10: bottom of 64-entry table
#define R2_HI  63.999996f      // bits 0x427FFFFF: top bin, bin index 531
#define BIN_LO 468             // (bits >> 21) of 2^-10
// 64 bins: 4 per octave (exp + 2 mantissa bits), 16 octaves

// f(r2) = exp(-sqrt(r2)) / (sqrt(r2) + b)  (table build only)
__device__ __forceinline__ float f_exact(float r2) {
    const float r = sqrtf(r2);
    return expf(-r) / (r + B_SOFT);
}
__device__ __forceinline__ unsigned to_bf16_rne(float v) {
    const unsigned b = __builtin_bit_cast(unsigned, v);
    return (b + 0x7FFFu + ((b >> 16) & 1u)) >> 16;
}
// rare-path exact f via native trans (rel err ~1e-4, only for r2 < 2^-10)
__device__ __forceinline__ float f_dev(float r2) {
    const float r = __builtin_amdgcn_sqrtf(r2);
    return __builtin_amdgcn_exp2f(-1.44269504f * r) *
           __builtin_amdgcn_rcpf(r + B_SOFT);
}

__global__ __launch_bounds__(BLOCK, 4)
void pot_energy_kernel(const float* __restrict__ x,
                       const float* __restrict__ neighbors,
                       const float* __restrict__ mask,
                       float* __restrict__ out, int B) {
    __shared__ float nbx[NSITES][RS];
    __shared__ float nby[NSITES][RS];
    __shared__ int   cnt[NSITES];

    const int tid  = threadIdx.x;
    const int wv   = tid >> 6;
    const int lane = tid & 63;

    // ---- per-wave REGISTER table: lane i holds bin (BIN_LO+i) ----
    // f ~= c + s*(r2 - bin_base), midpoint-corrected chord, bf16-packed.
    int tbl_pk;
    {
        const unsigned bin = (unsigned)(BIN_LO + lane);
        const float b0 = __builtin_bit_cast(float, bin << 21);
        const float b1 = __builtin_bit_cast(float, (bin + 1u) << 21);
        const float f0 = f_exact(b0);
        const float f1 = f_exact(b1);
        const float fm = f_exact(0.5f * (b0 + b1));
        const float s  = (f1 - f0) / (b1 - b0);
        const float fb = f0 - 0.5f * (0.5f * (f0 + f1) - fm);
        tbl_pk = (int)((to_bf16_rne(fb) << 16) | to_bf16_rne(s));
    }

    // Sentinel fill: entries past a site's count -> top bin -> ~4e-5 each.
    for (int idx = tid; idx < NSITES * RS; idx += BLOCK) {
        const int s = idx / RS, j = idx - s * RS;
        nbx[s][j] = PAD_C;
        nby[s][j] = PAD_C;
    }
    __syncthreads();

    // Ballot-compaction of neighbor lists into SoA LDS (~64 -> ~58).
    for (int s = wv; s < NSITES; s += 4) {
        const bool keep = mask[s * NMAX + lane] > 0.5f;
        const unsigned long long bal = __ballot(keep);
        if (keep) {
            const int pos = __popcll(bal & ((1ull << lane) - 1ull));
            const float2 p = ((const float2*)neighbors)[s * NMAX + lane];
            nbx[s][pos] = p.x;
            nby[s][pos] = p.y;
        }
        if (lane == 0) cnt[s] = __popcll(bal);
    }
    __syncthreads();

    // Uniform loop bound (identical in all lanes), multiple of 4.
    int m = 0;
    #pragma unroll
    for (int s = 0; s < NSITES; ++s) m = max(m, cnt[s]);
    m = (__builtin_amdgcn_readfirstlane(m) + 3) & ~3;   // <= 64

    const int gtid = blockIdx.x * BLOCK + tid;
    const int p    = gtid >> 2;   // pair id
    const int q    = gtid & 3;    // 3-site group
    const int half = B / ELEMS;
    if (p >= half) return;        // never taken at B=131072 (exact grid)
    const int e0 = p, e1 = p + half;

    float xs_[ELEMS][3], ys_[ELEMS][3];
    #pragma unroll
    for (int t = 0; t < ELEMS; ++t) {
        const int e = (t == 0) ? e0 : e1;
        const float2* xp = (const float2*)(x + (size_t)e * 24 + q * 6);
        const float2 p0 = xp[0], p1 = xp[1], p2 = xp[2];
        xs_[t][0] = p0.x; xs_[t][1] = p1.x; xs_[t][2] = p2.x;
        ys_[t][0] = p0.y; ys_[t][1] = p1.y; ys_[t][2] = p2.y;
    }

    float accC[ELEMS] = {0.f, 0.f}, accS[ELEMS] = {0.f, 0.f};
    #pragma unroll
    for (int s = 0; s < 3; ++s) {
        const int site = q * 3 + s;
        const float* __restrict__ rx = nbx[site];
        const float* __restrict__ ry = nby[site];
        #pragma unroll 2
        for (int j0 = 0; j0 < m; j0 += 4) {
            const float4 nx4 = *(const float4*)(rx + j0);
            const float4 ny4 = *(const float4*)(ry + j0);
            const float nx[4] = { nx4.x, nx4.y, nx4.z, nx4.w };
            const float ny[4] = { ny4.x, ny4.y, ny4.z, ny4.w };
            #pragma unroll
            for (int t = 0; t < ELEMS; ++t) {
                const float xs = xs_[t][s];
                const float ys = ys_[t][s];
                #pragma unroll
                for (int k = 0; k < 4; ++k) {
                    const float dx = xs - nx[k];
                    const float dy = ys - ny[k];
                    const float r2r = fmaf(dy, dy, dx * dx);
                    const float r2 =
                        __builtin_amdgcn_fmed3f(r2r, R2_LO, R2_HI);
                    const unsigned bits = __builtin_bit_cast(unsigned, r2);
                    // conflict-free register-table gather; low 2 addr bits
                    // are sub-bin junk, ignored by bpermute (>>2 inside)
                    const int addr = (int)(bits >> 19) - (BIN_LO << 2);
                    const int pk =
                        __builtin_amdgcn_ds_bpermute(addr, tbl_pk);
                    const float bb = __builtin_bit_cast(
                        float, bits & 0xFFE00000u);       // bin base
                    const float dr = r2 - bb;
                    float cv = __builtin_bit_cast(
                        float, (unsigned)pk & 0xFFFF0000u);
                    const float sl = __builtin_bit_cast(
                        float, (unsigned)pk << 16);
                    accS[t] = fmaf(sl, dr, accS[t]);      // always
                    if (r2r < R2_LO) {                    // rare (P~2e-5):
                        // patch: net contribution becomes exact f(r2r)
                        cv = f_dev(r2r) - sl * dr;
                    }
                    accC[t] += cv;
                }
            }
        }
    }

    #pragma unroll
    for (int t = 0; t < ELEMS; ++t) {
        float acc = accC[t] + accS[t];
        acc += __shfl_xor(acc, 1);   // combine q=0..3 partials
        acc += __shfl_xor(acc, 2);
        if (q == 0) out[(t == 0) ? e0 : e1] = acc;
    }
}

extern "C" void kernel_launch(void* const* d_in, const int* in_sizes, int n_in,
                              void* d_out, int out_size, void* d_ws, size_t ws_size,
                              hipStream_t stream) {
    const float* x   = (const float*)d_in[0];
    const float* nbr = (const float*)d_in[1];
    const float* msk = (const float*)d_in[2];
    float* out = (float*)d_out;

    const int B = in_sizes[0] / 24;
    const int total_threads = (B / ELEMS) * SPLIT;
    const int blocks = (total_threads + BLOCK - 1) / BLOCK;
    pot_energy_kernel<<<blocks, BLOCK, 0, stream>>>(x, nbr, msk, out, B);
}

// Round 11
// 87.960 us; speedup vs baseline: 1.2748x; 1.2748x over previous
//
#include <hip/hip_runtime.h>

#define NMAX   64
#define NSITES 12
#define SPLIT  4      // threads per element-pair slot (3 sites each)
#define ELEMS  2      // elements per thread (row reads amortized)
#define BLOCK  256
#define RS     68     // LDS row stride (floats): rows 16B-aligned

#define B_SOFT 0.01f
#define PAD_C  4.0e4f            // sentinel coord -> r2 ~3e9 -> clamped to top bin
#define R2_LO  0x1p-28f          // bottom of table: r = 2^-14 (f within 0.6 of f(0))
#define R2_HI  0x1.fffffep11f    // just below 4096: top bin, f ~ e^-64 ~ 0
#define KEY_LO 396               // (bits >> 21) of 2^-28
#define NBINS  160               // 4 bins/octave * 40 octaves
#define NCOPY  32                // one copy per LDS bank -> conflict-free gather

// f(r2) = exp(-sqrt(r2)) / (sqrt(r2) + b)   (table build only)
__device__ __forceinline__ float f_exact(float u) {
    const float r = sqrtf(u);
    return expf(-r) / (r + B_SOFT);
}
__device__ __forceinline__ unsigned to_bf16_rne(float v) {
    const unsigned b = __builtin_bit_cast(unsigned, v);
    return (b + 0x7FFFu + ((b >> 16) & 1u)) >> 16;
}

__global__ __launch_bounds__(BLOCK, 4)
void pot_energy_kernel(const float* __restrict__ x,
                       const float* __restrict__ neighbors,
                       const float* __restrict__ mask,
                       float* __restrict__ out, int B) {
    // Bank-replicated table: bin i, copy c at dword i*32+c. Lane l reads
    // copy (l&31) -> bank l&31 -> 32 distinct banks; lanes l and l+32
    // 2-way share (free). Random gather becomes flat-rate ds_read_b32.
    __shared__ unsigned tbl[NBINS * NCOPY];    // 20 KB
    __shared__ float    nbx[NSITES][RS];
    __shared__ float    nby[NSITES][RS];
    __shared__ int      cnt[NSITES];

    const int tid  = threadIdx.x;
    const int wv   = tid >> 6;
    const int lane = tid & 63;

    // Build: thread i computes bin i (i < 160), writes its 32 copies as
    // 8x b128. f ~= c + s*(r2 - bin_base), midpoint-corrected chord,
    // bf16-packed (c hi | s lo).
    if (tid < NBINS) {
        const unsigned key = (unsigned)(tid + KEY_LO);
        const float b0 = __builtin_bit_cast(float, key << 21);
        const float b1 = __builtin_bit_cast(float, (key + 1u) << 21);
        const float f0 = f_exact(b0);
        const float f1 = f_exact(b1);
        const float fm = f_exact(0.5f * (b0 + b1));
        const float s  = (f1 - f0) / (b1 - b0);
        const float c  = f0 - 0.5f * (0.5f * (f0 + f1) - fm);
        const unsigned pk = (to_bf16_rne(c) << 16) | to_bf16_rne(s);
        const uint4 v = make_uint4(pk, pk, pk, pk);
        uint4* dst = (uint4*)&tbl[tid * NCOPY];
        #pragma unroll
        for (int k = 0; k < 8; ++k) dst[k] = v;
    }

    // Sentinel fill: entries past a site's count -> top bin -> ~0 each.
    for (int idx = tid; idx < NSITES * RS; idx += BLOCK) {
        const int s = idx / RS, j = idx - s * RS;
        nbx[s][j] = PAD_C;
        nby[s][j] = PAD_C;
    }
    __syncthreads();

    // Ballot-compaction of neighbor lists into SoA LDS (~64 -> ~58).
    for (int s = wv; s < NSITES; s += 4) {
        const bool keep = mask[s * NMAX + lane] > 0.5f;
        const unsigned long long bal = __ballot(keep);
        if (keep) {
            const int pos = __popcll(bal & ((1ull << lane) - 1ull));
            const float2 p = ((const float2*)neighbors)[s * NMAX + lane];
            nbx[s][pos] = p.x;
            nby[s][pos] = p.y;
        }
        if (lane == 0) cnt[s] = __popcll(bal);
    }
    __syncthreads();

    // Uniform loop bound (identical in all lanes), multiple of 4.
    int m = 0;
    #pragma unroll
    for (int s = 0; s < NSITES; ++s) m = max(m, cnt[s]);
    m = (__builtin_amdgcn_readfirstlane(m) + 3) & ~3;   // <= 64

    const int gtid = blockIdx.x * BLOCK + tid;
    const int p    = gtid >> 2;   // pair id
    const int q    = gtid & 3;    // 3-site group
    const int half = B / ELEMS;
    if (p >= half) return;
    const int e0 = p, e1 = p + half;  // keeps loads/stores coalesced

    // Per-thread byte bias: copy select + table-base de-bias (hoisted).
    const unsigned bias = ((unsigned)(lane & 31) << 2)
                        - ((unsigned)KEY_LO << 7);

    float xs_[ELEMS][3], ys_[ELEMS][3];
    #pragma unroll
    for (int t = 0; t < ELEMS; ++t) {
        const int e = (t == 0) ? e0 : e1;
        const float2* xp = (const float2*)(x + (size_t)e * 24 + q * 6);
        const float2 p0 = xp[0], p1 = xp[1], p2 = xp[2];
        xs_[t][0] = p0.x; xs_[t][1] = p1.x; xs_[t][2] = p2.x;
        ys_[t][0] = p0.y; ys_[t][1] = p1.y; ys_[t][2] = p2.y;
    }

    float accC[ELEMS] = {0.f, 0.f}, accS[ELEMS] = {0.f, 0.f};
    #pragma unroll
    for (int s = 0; s < 3; ++s) {
        const int site = q * 3 + s;
        const float* __restrict__ rx = nbx[site];
        const float* __restrict__ ry = nby[site];
        #pragma unroll 2
        for (int j0 = 0; j0 < m; j0 += 4) {
            // one row-read pair feeds ELEMS*4 = 8 interactions
            const float4 nx4 = *(const float4*)(rx + j0);
            const float4 ny4 = *(const float4*)(ry + j0);
            const float nx[4] = { nx4.x, nx4.y, nx4.z, nx4.w };
            const float ny[4] = { ny4.x, ny4.y, ny4.z, ny4.w };
            #pragma unroll
            for (int t = 0; t < ELEMS; ++t) {
                const float xs = xs_[t][s];
                const float ys = ys_[t][s];
                #pragma unroll
                for (int k = 0; k < 4; ++k) {
                    const float dx = xs - nx[k];
                    const float dy = ys - ny[k];
                    const float r2r = fmaf(dy, dy, dx * dx);
                    const float r2 =
                        __builtin_amdgcn_fmed3f(r2r, R2_LO, R2_HI);
                    const unsigned bits = __builtin_bit_cast(unsigned, r2);
                    // byte offset ((bits>>21)<<7) + copy select - bias
                    const unsigned off = (bits >> 14) & 0xFFFFFF80u;
                    const unsigned pk = *(const unsigned*)(
                        (const char*)tbl + (off + bias));
                    const float bb = __builtin_bit_cast(
                        float, bits & 0xFFE00000u);       // bin base
                    const float dr = r2 - bb;
                    const float cv = __builtin_bit_cast(
                        float, pk & 0xFFFF0000u);
                    const float sl = __builtin_bit_cast(
                        float, pk << 16);
                    accC[t] += cv;
                    accS[t] = fmaf(sl, dr, accS[t]);
                }
            }
        }
    }

    #pragma unroll
    for (int t = 0; t < ELEMS; ++t) {
        float acc = accC[t] + accS[t];
        acc += __shfl_xor(acc, 1);   // combine q=0..3 partials
        acc += __shfl_xor(acc, 2);
        if (q == 0) out[(t == 0) ? e0 : e1] = acc;
    }
}

extern "C" void kernel_launch(void* const* d_in, const int* in_sizes, int n_in,
                              void* d_out, int out_size, void* d_ws, size_t ws_size,
                              hipStream_t stream) {
    const float* x   = (const float*)d_in[0];
    const float* nbr = (const float*)d_in[1];
    const float* msk = (const float*)d_in[2];
    float* out = (float*)d_out;

    const int B = in_sizes[0] / 24;
    const int total_threads = (B / ELEMS) * SPLIT;
    const int blocks = (total_threads + BLOCK - 1) / BLOCK;
    pot_energy_kernel<<<blocks, BLOCK, 0, stream>>>(x, nbr, msk, out, B);
}